// Round 9
// baseline (120.804 us; speedup 1.0000x reference)
//
#include <hip/hip_runtime.h>

#define TT 32
#define DIN 15
#define LOG2E 1.44269504088896340736f

typedef _Float16 f16x8 __attribute__((ext_vector_type(8)));
typedef _Float16 f16x4 __attribute__((ext_vector_type(4)));
typedef float f32x4 __attribute__((ext_vector_type(4)));

__device__ __forceinline__ float rcp_(float x){ return __builtin_amdgcn_rcpf(x); }
__device__ __forceinline__ float exp2_(float x){ return __builtin_amdgcn_exp2f(x); }
// safe tanh via rcp (never NaN on overflow); e-base (attention only)
__device__ __forceinline__ float tanh_(float x){ return fmaf(-2.f, rcp_(__expf(2.f*x)+1.f), 1.f); }

#define MFMA(a,b,c) __builtin_amdgcn_mfma_f32_16x16x32_f16(a,b,c,0,0,0)

__device__ __forceinline__ f16x8 f16x8_zero(){
  f16x8 v;
  #pragma unroll
  for (int j=0;j<8;++j) v[j]=(_Float16)0.f;
  return v;
}

// ---------------- prep: W -> f16 A-fragments (with gate prescales) + vq/vk ----------------
// chunk layout (16B units): whh1 @0, wih2 @1536, whh2 @3072: idx=((ht*3+g3)*2+kf)*64+lane
//   wih1 @4608 (kf=0, K padded 15->32, k=15 col = folded l1 biases): idx=(ht*3+g3)*64+lane
//   gat W1 @5376: idx=(ht*2+kf)*64+lane  (rows ht*16+(lane&15))
// r,z rows (g3<2) scaled by -LOG2E (sigm via exp2); n rows (g3==2) by 2*LOG2E (tanh via exp2).
// vqk[130]: vq[64]=Ww^T u[:64], vk[64]=Ww^T u[64:], cq=Wb.u[:64], ck=Wb.u[64:]
__global__ void wprep(const float* __restrict__ w1ih, const float* __restrict__ w1hh,
                      const float* __restrict__ w2ih, const float* __restrict__ w2hh,
                      const float* __restrict__ b1ih, const float* __restrict__ b1hh,
                      const float* __restrict__ W1,
                      const float* __restrict__ Ww, const float* __restrict__ Wb,
                      const float* __restrict__ u,
                      _Float16* __restrict__ wf, float* __restrict__ vqk){
  int id = blockIdx.x*256 + threadIdx.x;
  if (id < 47104){
    int e = id & 7, c = id >> 3;             // c: 0..5887
    float v, scale;
    if (c < 4608){
      int mat = c / 1536; int r = c - mat*1536;
      int lane = r & 63, kf = (r>>6)&1, q = r>>7;
      const float* W = (mat==0)? w1hh : (mat==1)? w2ih : w2hh;
      int ht = q/3, g3 = q - ht*3;
      int row = g3*64 + ht*16 + (lane & 15);
      int k = kf*32 + (lane>>4)*8 + e;
      v = W[row*64 + k];
      scale = (g3==2) ? 2.f*LOG2E : -LOG2E;
    } else if (c < 5376){
      int r = c - 4608; int lane = r & 63, q = r>>6;
      int ht = q/3, g3 = q - ht*3;
      int row = g3*64 + ht*16 + (lane & 15);
      int k = (lane>>4)*8 + e;
      if (k < DIN)       v = w1ih[row*DIN + k];
      else if (k == DIN) v = (g3 < 2) ? (b1ih[row] + b1hh[row]) : b1ih[row];
      else               v = 0.f;
      scale = (g3==2) ? 2.f*LOG2E : -LOG2E;
    } else {
      int r = c - 5376; int lane = r & 63, q = r>>6;   // q: 0..7
      int ht = q>>1, kf = q&1;
      int row = ht*16 + (lane & 15);
      int k = kf*32 + (lane>>4)*8 + e;
      v = W1[row*64 + k]; scale = 1.f;
    }
    wf[c*8 + e] = (_Float16)(v*scale);
  } else if (id < 47104 + 130){
    int t = id - 47104;
    if (t < 128){
      int which = t>>6, j = t&63;
      float s = 0.f;
      for (int i=0;i<64;++i) s = fmaf(u[which*64+i], Ww[i*64+j], s);
      vqk[t] = s;
    } else {
      int which = t-128;
      float s = 0.f;
      for (int i=0;i<64;++i) s = fmaf(u[which*64+i], Wb[i], s);
      vqk[128+which] = s;
    }
  }
}

// ---------------- fused 2-layer GRU + temporal attention + GAT projections ----------------
// grid 500 x 256 (4 waves). Block = one node (32 seqs = 2 seq-tiles/wave); wave = ht.
// 1 barrier/step (R7 pipeline, double-buffered LDS). REGISTER DIET to hit the 3-waves/SIMD
// quantum (<=170 unified regs: 84 AGPR weights + 32 acc + 16 staged frags + misc):
//  - h1/h2 f32 state regs eliminated: old state is read back from LDS as f16x4 at the
//    C/D-layout offset (also serves the attention numerator) — precision validated in R8.
//  - B-frags staged 2 at a time; l2 gate phase drains D-accs before l1 MFMAs start.
// 3 blocks/CU (LDS 3x52KB=156KB fits), 500 blocks resident in one round, 12 waves/CU.
__global__ __launch_bounds__(256, 3) void gru_mfma(
    const float* __restrict__ raw,
    const _Float16* __restrict__ wf,
    const float* __restrict__ vqk,
    const float* __restrict__ bhh1,
    const float* __restrict__ bih2, const float* __restrict__ bhh2,
    const float* __restrict__ attnW, const float* __restrict__ attnb,
    const float* __restrict__ W1b,
    _Float16* __restrict__ projh, float* __restrict__ sqT, float* __restrict__ skT)
{
  __shared__ _Float16 xfh[TT*64*8];     // 32KB: x B-frag chunks, (t*64 + g*32 + s)*8
  __shared__ _Float16 h1s[2][32*64];    // 8KB double-buffered, XOR-swizzled chunks
  __shared__ _Float16 h2s[2][32*64];    // 8KB
  __shared__ float bias2[256];          // l2 gate-init biases (prescaled)
  __shared__ float attp[2][2][4][16];   // [buf][seqtile][ht][sl]
  __shared__ float attq[4][32], attk[4][32];

  const int tid  = threadIdx.x;
  const int lane = tid & 63;
  const int ht   = tid >> 6;
  const int g    = lane >> 4;
  const int sl   = lane & 15;
  const int s7   = sl & 7;
  const int n    = blockIdx.x;
  const int seq0 = n*32;
  const int row0 = ht*16 + g*4;
  const int cwr  = (((ht*2+(g>>1)) ^ s7))*8 + (g&1)*4;   // swizzled C/D-layout f16x4 offset
  const int oT0  = sl*64, oT1 = (16+sl)*64;
  const int c0   = (g ^ s7)*8, c1 = ((4+g) ^ s7)*8;      // B-frag kf0/kf1 chunk offsets

  // ---- prologue staging ----
  { int* z2 = (int*)h2s[0]; for (int i=tid; i<1024; i+=256) z2[i]=0; }
  if (tid < 64){
    bias2[tid]       = -(bih2[tid]      + bhh2[tid])   *LOG2E;
    bias2[64+tid]    = -(bih2[64+tid]   + bhh2[64+tid])*LOG2E;
    bias2[128+tid]   =  bih2[128+tid]*(2.f*LOG2E);
    bias2[192+tid]   =  bhh2[128+tid]*(2.f*LOG2E);
  }
  for (int idx=tid; idx<TT*32; idx+=256){     // one (t,s) pair per iter
    int s = idx & 31, t = idx >> 5;
    const float* rp = &raw[(size_t)(seq0+s)*(TT*DIN) + t*DIN];
    f16x8 lo, hi;
    #pragma unroll
    for (int j=0;j<8;++j){
      lo[j] = (_Float16)rp[j];
      hi[j] = (j<7) ? (_Float16)rp[8+j] : (_Float16)1.0f;   // k=15 = bias channel
    }
    *(f16x8*)(xfh + ((size_t)t*64 +      s)*8) = lo;
    *(f16x8*)(xfh + ((size_t)t*64 + 32 + s)*8) = hi;
  }

  // ---- weight fragments (84 regs, live in AGPRs) ----
  const f16x8* wf8 = (const f16x8*)wf;
  f16x8 wr1_0 = wf8[((ht*3+0)*2+0)*64 + lane], wr1_1 = wf8[((ht*3+0)*2+1)*64 + lane];
  f16x8 wz1_0 = wf8[((ht*3+1)*2+0)*64 + lane], wz1_1 = wf8[((ht*3+1)*2+1)*64 + lane];
  f16x8 wn1_0 = wf8[((ht*3+2)*2+0)*64 + lane], wn1_1 = wf8[((ht*3+2)*2+1)*64 + lane];
  f16x8 ar2_0 = wf8[1536+((ht*3+0)*2+0)*64 + lane], ar2_1 = wf8[1536+((ht*3+0)*2+1)*64 + lane];
  f16x8 az2_0 = wf8[1536+((ht*3+1)*2+0)*64 + lane], az2_1 = wf8[1536+((ht*3+1)*2+1)*64 + lane];
  f16x8 an2_0 = wf8[1536+((ht*3+2)*2+0)*64 + lane], an2_1 = wf8[1536+((ht*3+2)*2+1)*64 + lane];
  f16x8 br2_0 = wf8[3072+((ht*3+0)*2+0)*64 + lane], br2_1 = wf8[3072+((ht*3+0)*2+1)*64 + lane];
  f16x8 bz2_0 = wf8[3072+((ht*3+1)*2+0)*64 + lane], bz2_1 = wf8[3072+((ht*3+1)*2+1)*64 + lane];
  f16x8 bn2_0 = wf8[3072+((ht*3+2)*2+0)*64 + lane], bn2_1 = wf8[3072+((ht*3+2)*2+1)*64 + lane];
  f16x8 xr1 = wf8[4608 + (ht*3+0)*64 + lane];
  f16x8 xz1 = wf8[4608 + (ht*3+1)*64 + lane];
  f16x8 xn1 = wf8[4608 + (ht*3+2)*64 + lane];

  f32x4 Bhn1, awv;
  #pragma unroll
  for (int r=0;r<4;++r){ Bhn1[r] = bhh1[128+row0+r]*(2.f*LOG2E); awv[r] = attnW[row0+r]; }
  const float ab = attnb[0];

  __syncthreads();   // B1: staging complete

  const f16x8 fz = f16x8_zero();
  f32x4 num0={0,0,0,0}, num1={0,0,0,0};
  float den0=0.f, den1=0.f;

  // ---- pipeline prologue: h1(0) from x(0) only (h1(-1)=0) ----
  {
    f16x8 xf0 = fz, xf1 = fz;
    if (g < 2){
      xf0 = *(const f16x8*)(xfh + ((size_t)0*64 + g*32 +      sl)*8);
      xf1 = *(const f16x8*)(xfh + ((size_t)0*64 + g*32 + 16 + sl)*8);
    }
    f32x4 Cr0={0,0,0,0}, Cz0={0,0,0,0}, Cxn0={0,0,0,0};
    f32x4 Cr1={0,0,0,0}, Cz1={0,0,0,0}, Cxn1={0,0,0,0};
    Cr0 = MFMA(xr1,xf0,Cr0); Cz0 = MFMA(xz1,xf0,Cz0); Cxn0 = MFMA(xn1,xf0,Cxn0);
    Cr1 = MFMA(xr1,xf1,Cr1); Cz1 = MFMA(xz1,xf1,Cz1); Cxn1 = MFMA(xn1,xf1,Cxn1);
    f16x4 hw0, hw1;
    #pragma unroll
    for (int r=0;r<4;++r){
      float rg0 = rcp_(1.f + exp2_(Cr0[r]));
      float zg0 = rcp_(1.f + exp2_(Cz0[r]));
      float ng0 = fmaf(-2.f, rcp_(exp2_(Cxn0[r] + rg0*Bhn1[r]) + 1.f), 1.f);
      hw0[r] = (_Float16)(ng0 - zg0*ng0);
      float rg1 = rcp_(1.f + exp2_(Cr1[r]));
      float zg1 = rcp_(1.f + exp2_(Cz1[r]));
      float ng1 = fmaf(-2.f, rcp_(exp2_(Cxn1[r] + rg1*Bhn1[r]) + 1.f), 1.f);
      hw1[r] = (_Float16)(ng1 - zg1*ng1);
    }
    *(f16x4*)(h1s[0] + oT0 + cwr) = hw0;
    *(f16x4*)(h1s[0] + oT1 + cwr) = hw1;
  }
  __syncthreads();   // B2: h1(0) visible

  // ---- main loop: 1 convergent barrier per step ----
  #pragma unroll 1
  for (int i=0; i<TT; ++i){
    const _Float16* h1rd = h1s[i&1];
    const _Float16* h2rd = h2s[i&1];
    _Float16* h1wr = h1s[(i+1)&1];
    _Float16* h2wr = h2s[(i+1)&1];
    // ---- h2(i-1) old state, C/D layout (attn numerator + l2 blend) ----
    f16x4 ho20 = *(const f16x4*)(h2rd + oT0 + cwr);
    f16x4 ho21 = *(const f16x4*)(h2rd + oT1 + cwr);
    // ---- attention finish for step i-1 ----
    if (i > 0){
      const float (*ap)[4][16] = attp[(i+1)&1];
      float s40 = ap[0][0][sl]+ap[0][1][sl]+ap[0][2][sl]+ap[0][3][sl];
      float s41 = ap[1][0][sl]+ap[1][1][sl]+ap[1][2][sl]+ap[1][3][sl];
      float e0 = __expf(tanh_(s40 + ab));
      float e1 = __expf(tanh_(s41 + ab));
      den0 += e0; den1 += e1;
      #pragma unroll
      for (int r=0;r<4;++r){
        num0[r] = fmaf(e0, (float)ho20[r], num0[r]);
        num1[r] = fmaf(e1, (float)ho21[r], num1[r]);
      }
    }
    // ---- layer2(i): 24 MFMAs, frags staged 2 at a time ----
    f32x4 Dr0  = *(const f32x4*)(bias2 + row0);
    f32x4 Dz0  = *(const f32x4*)(bias2 + 64 + row0);
    f32x4 Dxn0 = *(const f32x4*)(bias2 + 128 + row0);
    f32x4 Dhn0 = *(const f32x4*)(bias2 + 192 + row0);
    f32x4 Dr1 = Dr0, Dz1 = Dz0, Dxn1 = Dxn0, Dhn1 = Dhn0;
    {
      f16x8 p0 = *(const f16x8*)(h1rd + oT0 + c0);
      f16x8 p1 = *(const f16x8*)(h1rd + oT1 + c0);
      Dr0  = MFMA(ar2_0,p0,Dr0);  Dr1  = MFMA(ar2_0,p1,Dr1);
      Dz0  = MFMA(az2_0,p0,Dz0);  Dz1  = MFMA(az2_0,p1,Dz1);
      Dxn0 = MFMA(an2_0,p0,Dxn0); Dxn1 = MFMA(an2_0,p1,Dxn1);
      p0 = *(const f16x8*)(h1rd + oT0 + c1);
      p1 = *(const f16x8*)(h1rd + oT1 + c1);
      Dr0  = MFMA(ar2_1,p0,Dr0);  Dr1  = MFMA(ar2_1,p1,Dr1);
      Dz0  = MFMA(az2_1,p0,Dz0);  Dz1  = MFMA(az2_1,p1,Dz1);
      Dxn0 = MFMA(an2_1,p0,Dxn0); Dxn1 = MFMA(an2_1,p1,Dxn1);
      p0 = *(const f16x8*)(h2rd + oT0 + c0);
      p1 = *(const f16x8*)(h2rd + oT1 + c0);
      Dr0  = MFMA(br2_0,p0,Dr0);  Dr1  = MFMA(br2_0,p1,Dr1);
      Dz0  = MFMA(bz2_0,p0,Dz0);  Dz1  = MFMA(bz2_0,p1,Dz1);
      Dhn0 = MFMA(bn2_0,p0,Dhn0); Dhn1 = MFMA(bn2_0,p1,Dhn1);
      p0 = *(const f16x8*)(h2rd + oT0 + c1);
      p1 = *(const f16x8*)(h2rd + oT1 + c1);
      Dr0  = MFMA(br2_1,p0,Dr0);  Dr1  = MFMA(br2_1,p1,Dr1);
      Dz0  = MFMA(bz2_1,p0,Dz0);  Dz1  = MFMA(bz2_1,p1,Dz1);
      Dhn0 = MFMA(bn2_1,p0,Dhn0); Dhn1 = MFMA(bn2_1,p1,Dhn1);
    }
    // ---- gates l2 -> h2(i), attention partials (D-accs die here) ----
    {
      f16x4 hw0, hw1;
      float p0 = 0.f, p1 = 0.f;
      #pragma unroll
      for (int r=0;r<4;++r){
        float rg0 = rcp_(1.f + exp2_(Dr0[r]));
        float zg0 = rcp_(1.f + exp2_(Dz0[r]));
        float ng0 = fmaf(-2.f, rcp_(exp2_(Dxn0[r] + rg0*Dhn0[r]) + 1.f), 1.f);
        float h0  = ng0 + zg0*((float)ho20[r] - ng0);
        hw0[r] = (_Float16)h0; p0 = fmaf(h0, awv[r], p0);
        float rg1 = rcp_(1.f + exp2_(Dr1[r]));
        float zg1 = rcp_(1.f + exp2_(Dz1[r]));
        float ng1 = fmaf(-2.f, rcp_(exp2_(Dxn1[r] + rg1*Dhn1[r]) + 1.f), 1.f);
        float h1v = ng1 + zg1*((float)ho21[r] - ng1);
        hw1[r] = (_Float16)h1v; p1 = fmaf(h1v, awv[r], p1);
      }
      *(f16x4*)(h2wr + oT0 + cwr) = hw0;
      *(f16x4*)(h2wr + oT1 + cwr) = hw1;
      p0 += __shfl_xor(p0, 16, 64); p0 += __shfl_xor(p0, 32, 64);
      p1 += __shfl_xor(p1, 16, 64); p1 += __shfl_xor(p1, 32, 64);
      if (lane < 16){ attp[i&1][0][ht][sl] = p0; attp[i&1][1][ht][sl] = p1; }
    }
    // ---- layer1(i+1) = f(h1(i), x(i+1)) ----
    if (i < TT-1){
      f16x8 xf0 = fz, xf1 = fz;
      if (g < 2){
        xf0 = *(const f16x8*)(xfh + ((size_t)(i+1)*64 + g*32 +      sl)*8);
        xf1 = *(const f16x8*)(xfh + ((size_t)(i+1)*64 + g*32 + 16 + sl)*8);
      }
      f32x4 Cr0={0,0,0,0}, Cz0={0,0,0,0}, Cxn0={0,0,0,0}, Chn0=Bhn1;
      f32x4 Cr1={0,0,0,0}, Cz1={0,0,0,0}, Cxn1={0,0,0,0}, Chn1=Bhn1;
      {
        f16x8 p0 = *(const f16x8*)(h1rd + oT0 + c0);
        f16x8 p1 = *(const f16x8*)(h1rd + oT1 + c0);
        Cr0  = MFMA(wr1_0,p0,Cr0);  Cr1  = MFMA(wr1_0,p1,Cr1);
        Cz0  = MFMA(wz1_0,p0,Cz0);  Cz1  = MFMA(wz1_0,p1,Cz1);
        Chn0 = MFMA(wn1_0,p0,Chn0); Chn1 = MFMA(wn1_0,p1,Chn1);
        p0 = *(const f16x8*)(h1rd + oT0 + c1);
        p1 = *(const f16x8*)(h1rd + oT1 + c1);
        Cr0  = MFMA(wr1_1,p0,Cr0);  Cr1  = MFMA(wr1_1,p1,Cr1);
        Cz0  = MFMA(wz1_1,p0,Cz0);  Cz1  = MFMA(wz1_1,p1,Cz1);
        Chn0 = MFMA(wn1_1,p0,Chn0); Chn1 = MFMA(wn1_1,p1,Chn1);
      }
      Cr0  = MFMA(xr1,xf0,Cr0);  Cr1  = MFMA(xr1,xf1,Cr1);
      Cz0  = MFMA(xz1,xf0,Cz0);  Cz1  = MFMA(xz1,xf1,Cz1);
      Cxn0 = MFMA(xn1,xf0,Cxn0); Cxn1 = MFMA(xn1,xf1,Cxn1);
      // h1(i) old state, C/D layout
      f16x4 ho10 = *(const f16x4*)(h1rd + oT0 + cwr);
      f16x4 ho11 = *(const f16x4*)(h1rd + oT1 + cwr);
      f16x4 hw0, hw1;
      #pragma unroll
      for (int r=0;r<4;++r){
        float rg0 = rcp_(1.f + exp2_(Cr0[r]));
        float zg0 = rcp_(1.f + exp2_(Cz0[r]));
        float ng0 = fmaf(-2.f, rcp_(exp2_(Cxn0[r] + rg0*Chn0[r]) + 1.f), 1.f);
        float h0  = ng0 + zg0*((float)ho10[r] - ng0);
        hw0[r] = (_Float16)h0;
        float rg1 = rcp_(1.f + exp2_(Cr1[r]));
        float zg1 = rcp_(1.f + exp2_(Cz1[r]));
        float ng1 = fmaf(-2.f, rcp_(exp2_(Cxn1[r] + rg1*Chn1[r]) + 1.f), 1.f);
        float h1v = ng1 + zg1*((float)ho11[r] - ng1);
        hw1[r] = (_Float16)h1v;
      }
      *(f16x4*)(h1wr + oT0 + cwr) = hw0;
      *(f16x4*)(h1wr + oT1 + cwr) = hw1;
    }
    __syncthreads();
  }
  // ---- attention finish for t=TT-1 (h2(TT-1) in h2s[0], attp buffer 1) ----
  {
    f16x4 ho20 = *(const f16x4*)(h2s[0] + oT0 + cwr);
    f16x4 ho21 = *(const f16x4*)(h2s[0] + oT1 + cwr);
    const float (*ap)[4][16] = attp[1];
    float s40 = ap[0][0][sl]+ap[0][1][sl]+ap[0][2][sl]+ap[0][3][sl];
    float s41 = ap[1][0][sl]+ap[1][1][sl]+ap[1][2][sl]+ap[1][3][sl];
    float e0 = __expf(tanh_(s40 + ab));
    float e1 = __expf(tanh_(s41 + ab));
    den0 += e0; den1 += e1;
    #pragma unroll
    for (int r=0;r<4;++r){
      num0[r] = fmaf(e0, (float)ho20[r], num0[r]);
      num1[r] = fmaf(e1, (float)ho21[r], num1[r]);
    }
  }
  // ---- epilogue: Ai -> score partials + LDS B-frags (h1s[0] is free) ----
  float rd0 = rcp_(den0), rd1 = rcp_(den1);
  f32x4 av0, av1;
  #pragma unroll
  for (int r=0;r<4;++r){ av0[r] = num0[r]*rd0; av1[r] = num1[r]*rd1; }
  {
    f32x4 vq4 = *(const f32x4*)&vqk[row0];
    f32x4 vk4 = *(const f32x4*)&vqk[64+row0];
    float pq0=0.f, pk0=0.f, pq1=0.f, pk1=0.f;
    #pragma unroll
    for (int r=0;r<4;++r){
      pq0 = fmaf(av0[r], vq4[r], pq0); pk0 = fmaf(av0[r], vk4[r], pk0);
      pq1 = fmaf(av1[r], vq4[r], pq1); pk1 = fmaf(av1[r], vk4[r], pk1);
    }
    pq0 += __shfl_xor(pq0,16,64); pq0 += __shfl_xor(pq0,32,64);
    pk0 += __shfl_xor(pk0,16,64); pk0 += __shfl_xor(pk0,32,64);
    pq1 += __shfl_xor(pq1,16,64); pq1 += __shfl_xor(pq1,32,64);
    pk1 += __shfl_xor(pk1,16,64); pk1 += __shfl_xor(pk1,32,64);
    if (lane < 16){
      attq[ht][sl] = pq0;    attk[ht][sl] = pk0;
      attq[ht][16+sl] = pq1; attk[ht][16+sl] = pk1;
    }
  }
  { f16x4 af0, af1;
    #pragma unroll
    for (int r=0;r<4;++r){ af0[r] = (_Float16)av0[r]; af1[r] = (_Float16)av1[r]; }
    *(f16x4*)(h1s[0] + oT0 + cwr) = af0;
    *(f16x4*)(h1s[0] + oT1 + cwr) = af1; }
  __syncthreads();
  // ---- scores out (pre-scaled by LOG2E for exp2 in agg) ----
  if (tid < 32){
    float q4 = attq[0][tid]+attq[1][tid]+attq[2][tid]+attq[3][tid];
    float k4 = attk[0][tid]+attk[1][tid]+attk[2][tid]+attk[3][tid];
    sqT[tid*512 + n] = (q4 + vqk[128])*LOG2E;
    skT[tid*512 + n] = (k4 + vqk[129])*LOG2E;
  }
  // ---- proj = Ai @ W1^T + W1b via 2 MFMAs per seq-tile, store f16 ----
  {
    f16x8 a0 = wf8[5376 + (ht*2+0)*64 + lane];
    f16x8 a1 = wf8[5376 + (ht*2+1)*64 + lane];
    f16x8 b00 = *(const f16x8*)(h1s[0] + oT0 + c0);
    f16x8 b01 = *(const f16x8*)(h1s[0] + oT0 + c1);
    f16x8 b10 = *(const f16x8*)(h1s[0] + oT1 + c0);
    f16x8 b11 = *(const f16x8*)(h1s[0] + oT1 + c1);
    f32x4 P0 = *(const f32x4*)&W1b[row0];
    f32x4 P1 = P0;
    P0 = MFMA(a0,b00,P0); P0 = MFMA(a1,b01,P0);
    P1 = MFMA(a0,b10,P1); P1 = MFMA(a1,b11,P1);
    f16x4 pf0, pf1;
    #pragma unroll
    for (int r=0;r<4;++r){ pf0[r] = (_Float16)P0[r]; pf1[r] = (_Float16)P1[r]; }
    *(f16x4*)(projh + (size_t)(seq0+sl)*64    + row0) = pf0;
    *(f16x4*)(projh + (size_t)(seq0+16+sl)*64 + row0) = pf1;
  }
}

// ---------------- GAT aggregation: MFMA PV over (q x k) per batch-col ----------------
// grid 256 = 8 q-tiles(64) x 32 b; 256 thr, wave = q-sub of 16.
// O^T[d,q] = sum_k projT[d,k] * E[k-col q]; E computed in-register in B-frag layout.
__global__ __launch_bounds__(256) void gat_agg(
    const _Float16* __restrict__ projh,
    const float* __restrict__ sqT, const float* __restrict__ skT,
    float* __restrict__ out)
{
  __shared__ _Float16 pT[64*64];   // [d][k] chunk-XOR-swizzled, 8KB
  __shared__ float sks[512];
  const int tid  = threadIdx.x;
  const int lane = tid & 63;
  const int wv   = tid >> 6;
  const int b    = blockIdx.x & 31;
  const int qt   = blockIdx.x >> 5;
  const int sl   = lane & 15, g = lane >> 4;
  const int myq  = qt*64 + wv*16 + sl;
  const float sq_l = (myq < 500) ? sqT[b*512 + myq] : -1e30f;
  for (int j = tid; j < 512; j += 256) sks[j] = (j < 500) ? skT[b*512 + j] : -1e30f;

  f32x4 acc[4] = {{0,0,0,0},{0,0,0,0},{0,0,0,0},{0,0,0,0}};
  float den_l = 0.f;
  const int kr = tid & 63, dgrp = tid >> 6;

  // prefetch chunk 0
  f16x8 pv0 = f16x8_zero(), pv1 = f16x8_zero();
  if (kr < 500){
    const f16x8* pp = (const f16x8*)(projh + ((size_t)kr*32 + b)*64 + dgrp*16);
    pv0 = pp[0]; pv1 = pp[1];
  }

  #pragma unroll 1
  for (int kc=0; kc<8; ++kc){
    __syncthreads();   // pT free (previous chunk consumed)
    // transpose-write: element (k=kr, d=dgrp*16+j) -> byte d*128 + ((kr>>3 ^ d&7)<<4) + (kr&7)*2
    { char* base = (char*)pT;
      const int klo = (kr & 7) << 1, khi = kr >> 3;
      #pragma unroll
      for (int j=0;j<16;++j){
        int d = dgrp*16 + j;
        _Float16 v = (j<8) ? pv0[j] : pv1[j-8];
        *(_Float16*)(base + d*128 + (((khi ^ (d&7))) << 4) + klo) = v;
      } }
    __syncthreads();
    // prefetch next chunk (latency hides under compute)
    if (kc < 7){
      int node = (kc+1)*64 + kr;
      if (node < 500){
        const f16x8* pp = (const f16x8*)(projh + ((size_t)node*32 + b)*64 + dgrp*16);
        pv0 = pp[0]; pv1 = pp[1];
      } else { pv0 = f16x8_zero(); pv1 = f16x8_zero(); }
    }
    // compute: 2 k32-subchunks x 4 d-tiles
    #pragma unroll
    for (int kc32=0; kc32<2; ++kc32){
      const int kb = kc*64 + kc32*32 + g*8;
      float4 skv0 = *(const float4*)&sks[kb];
      float4 skv1 = *(const float4*)&sks[kb+4];
      float s[8] = {sq_l+skv0.x, sq_l+skv0.y, sq_l+skv0.z, sq_l+skv0.w,
                    sq_l+skv1.x, sq_l+skv1.y, sq_l+skv1.z, sq_l+skv1.w};
      f16x8 bf;
      #pragma unroll
      for (int e=0;e<8;++e){
        float sc = fmaxf(s[e], 0.01f*s[e]);   // leaky_relu (scale-commuting)
        float ev = exp2_(sc);
        den_l += ev;
        bf[e] = (_Float16)ev;
      }
      const char* base = (const char*)pT;
      #pragma unroll
      for (int dt=0; dt<4; ++dt){
        f16x8 a = *(const f16x8*)(base + (dt*16 + sl)*128 + (((kc32*4 + g) ^ (sl&7)) << 4));
        acc[dt] = MFMA(a, bf, acc[dt]);
      }
    }
  }
  den_l += __shfl_xor(den_l, 16, 64);
  den_l += __shfl_xor(den_l, 32, 64);
  const float rd = rcp_(den_l);
  if (myq < 500){
    #pragma unroll
    for (int dt=0; dt<4; ++dt){
      f32x4 o;
      #pragma unroll
      for (int r=0;r<4;++r) o[r] = fmaxf(acc[dt][r]*rd, 0.f);
      *(f32x4*)&out[((size_t)myq*32 + b)*64 + dt*16 + g*4] = o;
    }
  }
}

extern "C" void kernel_launch(void* const* d_in, const int* in_sizes, int n_in,
                              void* d_out, int out_size, void* d_ws, size_t ws_size,
                              hipStream_t stream) {
  const float* raw   = (const float*)d_in[0];
  const float* w1ih  = (const float*)d_in[1];
  const float* w1hh  = (const float*)d_in[2];
  const float* b1ih  = (const float*)d_in[3];
  const float* b1hh  = (const float*)d_in[4];
  const float* w2ih  = (const float*)d_in[5];
  const float* w2hh  = (const float*)d_in[6];
  const float* b2ih  = (const float*)d_in[7];
  const float* b2hh  = (const float*)d_in[8];
  const float* attW  = (const float*)d_in[9];
  const float* attb  = (const float*)d_in[10];
  const float* gWw   = (const float*)d_in[11];
  const float* gWb   = (const float*)d_in[12];
  const float* gu    = (const float*)d_in[13];
  const float* gW1   = (const float*)d_in[14];
  const float* gW1b  = (const float*)d_in[15];
  float* outp = (float*)d_out;

  char* wsb = (char*)d_ws;
  _Float16* projh = (_Float16*)wsb;                           // 2,048,000 B
  float*    sqT   = (float*)(wsb + 2048000);                  // 65,536 B [32][512]
  float*    skT   = (float*)(wsb + 2048000 + 65536);          // 65,536 B
  _Float16* wfh   = (_Float16*)(wsb + 2048000 + 131072);      // 94,208 B (5888 chunks)
  float*    vqk   = (float*)(wsb + 2048000 + 131072 + 94208); // 520 B

  wprep<<<185, 256, 0, stream>>>(w1ih, w1hh, w2ih, w2hh, b1ih, b1hh,
                                 gW1, gWw, gWb, gu, wfh, vqk);
  gru_mfma<<<500, 256, 0, stream>>>(raw, wfh, vqk, b1hh, b2ih, b2hh,
                                    attW, attb, gW1b, projh, sqT, skT);
  gat_agg<<<256, 256, 0, stream>>>(projh, sqT, skT, outp);
}

// Round 10
// 89.108 us; speedup vs baseline: 1.3557x; 1.3557x over previous
//
#include <hip/hip_runtime.h>

#define TT 32
#define DIN 15
#define LOG2E 1.44269504088896340736f

typedef _Float16 f16x8 __attribute__((ext_vector_type(8)));
typedef _Float16 f16x4 __attribute__((ext_vector_type(4)));
typedef float f32x4 __attribute__((ext_vector_type(4)));

__device__ __forceinline__ float rcp_(float x){ return __builtin_amdgcn_rcpf(x); }
__device__ __forceinline__ float exp2_(float x){ return __builtin_amdgcn_exp2f(x); }
// safe tanh via rcp (never NaN on overflow); e-base (attention only)
__device__ __forceinline__ float tanh_(float x){ return fmaf(-2.f, rcp_(__expf(2.f*x)+1.f), 1.f); }

#define MFMA(a,b,c) __builtin_amdgcn_mfma_f32_16x16x32_f16(a,b,c,0,0,0)

__device__ __forceinline__ f16x8 f16x8_zero(){
  f16x8 v;
  #pragma unroll
  for (int j=0;j<8;++j) v[j]=(_Float16)0.f;
  return v;
}

// ---------------- prep: W -> f16 A-fragments (with gate prescales) + vq/vk ----------------
// chunk layout (16B units): whh1 @0, wih2 @1536, whh2 @3072: idx=((ht*3+g3)*2+kf)*64+lane
//   wih1 @4608 (kf=0, K padded 15->32, k=15 col = folded l1 biases): idx=(ht*3+g3)*64+lane
//   gat W1 @5376: idx=(ht*2+kf)*64+lane  (rows ht*16+(lane&15))
// r,z rows (g3<2) scaled by -LOG2E (sigm via exp2); n rows (g3==2) by 2*LOG2E (tanh via exp2).
// vqk[130]: vq[64]=Ww^T u[:64], vk[64]=Ww^T u[64:], cq=Wb.u[:64], ck=Wb.u[64:]
__global__ void wprep(const float* __restrict__ w1ih, const float* __restrict__ w1hh,
                      const float* __restrict__ w2ih, const float* __restrict__ w2hh,
                      const float* __restrict__ b1ih, const float* __restrict__ b1hh,
                      const float* __restrict__ W1,
                      const float* __restrict__ Ww, const float* __restrict__ Wb,
                      const float* __restrict__ u,
                      _Float16* __restrict__ wf, float* __restrict__ vqk){
  int id = blockIdx.x*256 + threadIdx.x;
  if (id < 47104){
    int e = id & 7, c = id >> 3;             // c: 0..5887
    float v, scale;
    if (c < 4608){
      int mat = c / 1536; int r = c - mat*1536;
      int lane = r & 63, kf = (r>>6)&1, q = r>>7;
      const float* W = (mat==0)? w1hh : (mat==1)? w2ih : w2hh;
      int ht = q/3, g3 = q - ht*3;
      int row = g3*64 + ht*16 + (lane & 15);
      int k = kf*32 + (lane>>4)*8 + e;
      v = W[row*64 + k];
      scale = (g3==2) ? 2.f*LOG2E : -LOG2E;
    } else if (c < 5376){
      int r = c - 4608; int lane = r & 63, q = r>>6;
      int ht = q/3, g3 = q - ht*3;
      int row = g3*64 + ht*16 + (lane & 15);
      int k = (lane>>4)*8 + e;
      if (k < DIN)       v = w1ih[row*DIN + k];
      else if (k == DIN) v = (g3 < 2) ? (b1ih[row] + b1hh[row]) : b1ih[row];
      else               v = 0.f;
      scale = (g3==2) ? 2.f*LOG2E : -LOG2E;
    } else {
      int r = c - 5376; int lane = r & 63, q = r>>6;   // q: 0..7
      int ht = q>>1, kf = q&1;
      int row = ht*16 + (lane & 15);
      int k = kf*32 + (lane>>4)*8 + e;
      v = W1[row*64 + k]; scale = 1.f;
    }
    wf[c*8 + e] = (_Float16)(v*scale);
  } else if (id < 47104 + 130){
    int t = id - 47104;
    if (t < 128){
      int which = t>>6, j = t&63;
      float s = 0.f;
      for (int i=0;i<64;++i) s = fmaf(u[which*64+i], Ww[i*64+j], s);
      vqk[t] = s;
    } else {
      int which = t-128;
      float s = 0.f;
      for (int i=0;i<64;++i) s = fmaf(u[which*64+i], Wb[i], s);
      vqk[128+which] = s;
    }
  }
}

// ---------------- fused 2-layer GRU + temporal attention + GAT projections ----------------
// grid 500 x 256 (4 waves). Block = one node (32 seqs = 2 seq-tiles/wave); wave = ht.
// R6 structure (best measured: 85us gru, no spill): 2 blocks/CU in the 256-reg quantum,
// 500 blocks fully resident. R4/R5/R8/R9 all proved >2 waves/SIMD spills (84-reg weight
// set + ~100-reg working set > 170). Added: s_setprio(1) around MFMA clusters — 2
// independent blocks/CU at different phases give the CU scheduler role diversity.
__global__ __launch_bounds__(256, 2) void gru_mfma(
    const float* __restrict__ raw,
    const _Float16* __restrict__ wf,
    const float* __restrict__ vqk,
    const float* __restrict__ bhh1,
    const float* __restrict__ bih2, const float* __restrict__ bhh2,
    const float* __restrict__ attnW, const float* __restrict__ attnb,
    const float* __restrict__ W1b,
    _Float16* __restrict__ projh, float* __restrict__ sqT, float* __restrict__ skT)
{
  __shared__ _Float16 xfh[TT*64*8];   // 32KB: x B-frag chunks, (t*64 + g*32 + s)*8, g=k-half
  __shared__ _Float16 h1s[32*64];     // 4KB, XOR-swizzled chunks
  __shared__ _Float16 h2s[32*64];     // 4KB
  __shared__ float bias2[256];        // l2 gate-init biases (prescaled)
  __shared__ float attp[2][4][16];
  __shared__ float attq[4][32], attk[4][32];

  const int tid  = threadIdx.x;
  const int lane = tid & 63;
  const int ht   = tid >> 6;
  const int g    = lane >> 4;
  const int sl   = lane & 15;
  const int s7   = sl & 7;
  const int n    = blockIdx.x;
  const int seq0 = n*32;
  const int row0 = ht*16 + g*4;

  // ---- prologue ----
  { int* z2 = (int*)h2s; for (int i=tid; i<1024; i+=256) z2[i]=0; }
  if (tid < 64){
    bias2[tid]       = -(bih2[tid]      + bhh2[tid])   *LOG2E;
    bias2[64+tid]    = -(bih2[64+tid]   + bhh2[64+tid])*LOG2E;
    bias2[128+tid]   =  bih2[128+tid]*(2.f*LOG2E);
    bias2[192+tid]   =  bhh2[128+tid]*(2.f*LOG2E);
  }
  for (int idx=tid; idx<TT*32; idx+=256){     // one (t,s) pair per iter
    int s = idx & 31, t = idx >> 5;
    const float* rp = &raw[(size_t)(seq0+s)*(TT*DIN) + t*DIN];
    f16x8 lo, hi;
    #pragma unroll
    for (int j=0;j<8;++j){
      lo[j] = (_Float16)rp[j];
      hi[j] = (j<7) ? (_Float16)rp[8+j] : (_Float16)1.0f;   // k=15 = bias channel
    }
    *(f16x8*)(xfh + ((size_t)t*64 +      s)*8) = lo;
    *(f16x8*)(xfh + ((size_t)t*64 + 32 + s)*8) = hi;
  }

  // ---- weight fragments (84 regs, live in AGPRs) ----
  const f16x8* wf8 = (const f16x8*)wf;
  f16x8 wr1_0 = wf8[((ht*3+0)*2+0)*64 + lane], wr1_1 = wf8[((ht*3+0)*2+1)*64 + lane];
  f16x8 wz1_0 = wf8[((ht*3+1)*2+0)*64 + lane], wz1_1 = wf8[((ht*3+1)*2+1)*64 + lane];
  f16x8 wn1_0 = wf8[((ht*3+2)*2+0)*64 + lane], wn1_1 = wf8[((ht*3+2)*2+1)*64 + lane];
  f16x8 ar2_0 = wf8[1536+((ht*3+0)*2+0)*64 + lane], ar2_1 = wf8[1536+((ht*3+0)*2+1)*64 + lane];
  f16x8 az2_0 = wf8[1536+((ht*3+1)*2+0)*64 + lane], az2_1 = wf8[1536+((ht*3+1)*2+1)*64 + lane];
  f16x8 an2_0 = wf8[1536+((ht*3+2)*2+0)*64 + lane], an2_1 = wf8[1536+((ht*3+2)*2+1)*64 + lane];
  f16x8 br2_0 = wf8[3072+((ht*3+0)*2+0)*64 + lane], br2_1 = wf8[3072+((ht*3+0)*2+1)*64 + lane];
  f16x8 bz2_0 = wf8[3072+((ht*3+1)*2+0)*64 + lane], bz2_1 = wf8[3072+((ht*3+1)*2+1)*64 + lane];
  f16x8 bn2_0 = wf8[3072+((ht*3+2)*2+0)*64 + lane], bn2_1 = wf8[3072+((ht*3+2)*2+1)*64 + lane];
  f16x8 xr1 = wf8[4608 + (ht*3+0)*64 + lane];
  f16x8 xz1 = wf8[4608 + (ht*3+1)*64 + lane];
  f16x8 xn1 = wf8[4608 + (ht*3+2)*64 + lane];

  f32x4 Bhn1, awv;
  #pragma unroll
  for (int r=0;r<4;++r){ Bhn1[r] = bhh1[128+row0+r]*(2.f*LOG2E); awv[r] = attnW[row0+r]; }
  const float ab = attnb[0];

  __syncthreads();

  const f16x8 fz = f16x8_zero();
  f16x8 h1f0_0=fz, h1f0_1=fz, h1f1_0=fz, h1f1_1=fz;
  f32x4 h1c0={0,0,0,0}, h1c1={0,0,0,0}, h2c0={0,0,0,0}, h2c1={0,0,0,0};
  f32x4 num0={0,0,0,0}, num1={0,0,0,0};
  float den0=0.f, den1=0.f;

  #pragma unroll 1
  for (int t=0; t<TT; ++t){
    // ---- fresh B-fragments (pre-barrier-A reads) ----
    f16x8 xf0 = fz, xf1 = fz;
    if (g < 2){
      xf0 = *(const f16x8*)(xfh + ((size_t)t*64 + g*32 +      sl)*8);
      xf1 = *(const f16x8*)(xfh + ((size_t)t*64 + g*32 + 16 + sl)*8);
    }
    f16x8 h2f0_0 = *(const f16x8*)(h2s + sl*64      + ((g    ^s7))*8);
    f16x8 h2f0_1 = *(const f16x8*)(h2s + sl*64      + (((4+g)^s7))*8);
    f16x8 h2f1_0 = *(const f16x8*)(h2s + (16+sl)*64 + ((g    ^s7))*8);
    f16x8 h2f1_1 = *(const f16x8*)(h2s + (16+sl)*64 + (((4+g)^s7))*8);
    if (t > 0){
      float s40 = attp[0][0][sl]+attp[0][1][sl]+attp[0][2][sl]+attp[0][3][sl];
      float s41 = attp[1][0][sl]+attp[1][1][sl]+attp[1][2][sl]+attp[1][3][sl];
      float e0 = __expf(tanh_(s40 + ab));
      float e1 = __expf(tanh_(s41 + ab));
      den0 += e0; den1 += e1;
      #pragma unroll
      for (int r=0;r<4;++r){
        num0[r] = fmaf(e0, h2c0[r], num0[r]);
        num1[r] = fmaf(e1, h2c1[r], num1[r]);
      }
    }
    // ---- layer1: 9 MFMAs per seq-tile ----
    f32x4 Cr0={0,0,0,0}, Cz0={0,0,0,0}, Cxn0={0,0,0,0}, Chn0=Bhn1;
    f32x4 Cr1={0,0,0,0}, Cz1={0,0,0,0}, Cxn1={0,0,0,0}, Chn1=Bhn1;
    __builtin_amdgcn_s_setprio(1);
    Cr0 = MFMA(wr1_0,h1f0_0,Cr0); Cr0 = MFMA(wr1_1,h1f0_1,Cr0); Cr0 = MFMA(xr1,xf0,Cr0);
    Cr1 = MFMA(wr1_0,h1f1_0,Cr1); Cr1 = MFMA(wr1_1,h1f1_1,Cr1); Cr1 = MFMA(xr1,xf1,Cr1);
    Cz0 = MFMA(wz1_0,h1f0_0,Cz0); Cz0 = MFMA(wz1_1,h1f0_1,Cz0); Cz0 = MFMA(xz1,xf0,Cz0);
    Cz1 = MFMA(wz1_0,h1f1_0,Cz1); Cz1 = MFMA(wz1_1,h1f1_1,Cz1); Cz1 = MFMA(xz1,xf1,Cz1);
    Chn0 = MFMA(wn1_0,h1f0_0,Chn0); Chn0 = MFMA(wn1_1,h1f0_1,Chn0);
    Chn1 = MFMA(wn1_0,h1f1_0,Chn1); Chn1 = MFMA(wn1_1,h1f1_1,Chn1);
    Cxn0 = MFMA(xn1,xf0,Cxn0);
    Cxn1 = MFMA(xn1,xf1,Cxn1);
    __builtin_amdgcn_s_setprio(0);
    // ---- gates l1 -> h1_new (f16) ----
    f16x4 hw0, hw1;
    #pragma unroll
    for (int r=0;r<4;++r){
      float rg0 = rcp_(1.f + exp2_(Cr0[r]));
      float zg0 = rcp_(1.f + exp2_(Cz0[r]));
      float ng0 = fmaf(-2.f, rcp_(exp2_(Cxn0[r] + rg0*Chn0[r]) + 1.f), 1.f);
      float h0  = ng0 + zg0*(h1c0[r] - ng0);
      h1c0[r] = h0; hw0[r] = (_Float16)h0;
      float rg1 = rcp_(1.f + exp2_(Cr1[r]));
      float zg1 = rcp_(1.f + exp2_(Cz1[r]));
      float ng1 = fmaf(-2.f, rcp_(exp2_(Cxn1[r] + rg1*Chn1[r]) + 1.f), 1.f);
      float h1v = ng1 + zg1*(h1c1[r] - ng1);
      h1c1[r] = h1v; hw1[r] = (_Float16)h1v;
    }
    { const int cw = (((ht*2+(g>>1)) ^ s7))*8 + (g&1)*4;
      *(f16x4*)(h1s + sl*64      + cw) = hw0;
      *(f16x4*)(h1s + (16+sl)*64 + cw) = hw1; }
    __syncthreads();   // A: h1_new visible; orders h2 reads before h2 writes
    h1f0_0 = *(const f16x8*)(h1s + sl*64      + ((g    ^s7))*8);
    h1f0_1 = *(const f16x8*)(h1s + sl*64      + (((4+g)^s7))*8);
    h1f1_0 = *(const f16x8*)(h1s + (16+sl)*64 + ((g    ^s7))*8);
    h1f1_1 = *(const f16x8*)(h1s + (16+sl)*64 + (((4+g)^s7))*8);
    // ---- layer2: 12 MFMAs per seq-tile ----
    f32x4 Dr0  = *(const f32x4*)(bias2 + row0);
    f32x4 Dz0  = *(const f32x4*)(bias2 + 64 + row0);
    f32x4 Dxn0 = *(const f32x4*)(bias2 + 128 + row0);
    f32x4 Dhn0 = *(const f32x4*)(bias2 + 192 + row0);
    f32x4 Dr1 = Dr0, Dz1 = Dz0, Dxn1 = Dxn0, Dhn1 = Dhn0;
    __builtin_amdgcn_s_setprio(1);
    Dr0  = MFMA(ar2_0,h1f0_0,Dr0);  Dr0  = MFMA(ar2_1,h1f0_1,Dr0);
    Dr0  = MFMA(br2_0,h2f0_0,Dr0);  Dr0  = MFMA(br2_1,h2f0_1,Dr0);
    Dr1  = MFMA(ar2_0,h1f1_0,Dr1);  Dr1  = MFMA(ar2_1,h1f1_1,Dr1);
    Dr1  = MFMA(br2_0,h2f1_0,Dr1);  Dr1  = MFMA(br2_1,h2f1_1,Dr1);
    Dz0  = MFMA(az2_0,h1f0_0,Dz0);  Dz0  = MFMA(az2_1,h1f0_1,Dz0);
    Dz0  = MFMA(bz2_0,h2f0_0,Dz0);  Dz0  = MFMA(bz2_1,h2f0_1,Dz0);
    Dz1  = MFMA(az2_0,h1f1_0,Dz1);  Dz1  = MFMA(az2_1,h1f1_1,Dz1);
    Dz1  = MFMA(bz2_0,h2f1_0,Dz1);  Dz1  = MFMA(bz2_1,h2f1_1,Dz1);
    Dxn0 = MFMA(an2_0,h1f0_0,Dxn0); Dxn0 = MFMA(an2_1,h1f0_1,Dxn0);
    Dxn1 = MFMA(an2_0,h1f1_0,Dxn1); Dxn1 = MFMA(an2_1,h1f1_1,Dxn1);
    Dhn0 = MFMA(bn2_0,h2f0_0,Dhn0); Dhn0 = MFMA(bn2_1,h2f0_1,Dhn0);
    Dhn1 = MFMA(bn2_0,h2f1_0,Dhn1); Dhn1 = MFMA(bn2_1,h2f1_1,Dhn1);
    __builtin_amdgcn_s_setprio(0);
    // ---- gates l2 -> h2_new, attention partials ----
    float p0 = 0.f, p1 = 0.f;
    #pragma unroll
    for (int r=0;r<4;++r){
      float rg0 = rcp_(1.f + exp2_(Dr0[r]));
      float zg0 = rcp_(1.f + exp2_(Dz0[r]));
      float ng0 = fmaf(-2.f, rcp_(exp2_(Dxn0[r] + rg0*Dhn0[r]) + 1.f), 1.f);
      float h0  = ng0 + zg0*(h2c0[r] - ng0);
      h2c0[r] = h0; hw0[r] = (_Float16)h0;
      p0 = fmaf(h0, awv[r], p0);
      float rg1 = rcp_(1.f + exp2_(Dr1[r]));
      float zg1 = rcp_(1.f + exp2_(Dz1[r]));
      float ng1 = fmaf(-2.f, rcp_(exp2_(Dxn1[r] + rg1*Dhn1[r]) + 1.f), 1.f);
      float h1v = ng1 + zg1*(h2c1[r] - ng1);
      h2c1[r] = h1v; hw1[r] = (_Float16)h1v;
      p1 = fmaf(h1v, awv[r], p1);
    }
    { const int cw = (((ht*2+(g>>1)) ^ s7))*8 + (g&1)*4;
      *(f16x4*)(h2s + sl*64      + cw) = hw0;
      *(f16x4*)(h2s + (16+sl)*64 + cw) = hw1; }
    p0 += __shfl_xor(p0, 16, 64); p0 += __shfl_xor(p0, 32, 64);
    p1 += __shfl_xor(p1, 16, 64); p1 += __shfl_xor(p1, 32, 64);
    if (lane < 16){ attp[0][ht][sl] = p0; attp[1][ht][sl] = p1; }
    __syncthreads();   // B: h2_new + attp visible
  }
  // ---- finish attention (t=TT-1) ----
  {
    float s40 = attp[0][0][sl]+attp[0][1][sl]+attp[0][2][sl]+attp[0][3][sl];
    float s41 = attp[1][0][sl]+attp[1][1][sl]+attp[1][2][sl]+attp[1][3][sl];
    float e0 = __expf(tanh_(s40 + ab));
    float e1 = __expf(tanh_(s41 + ab));
    den0 += e0; den1 += e1;
    #pragma unroll
    for (int r=0;r<4;++r){
      num0[r] = fmaf(e0, h2c0[r], num0[r]);
      num1[r] = fmaf(e1, h2c1[r], num1[r]);
    }
  }
  // ---- epilogue: Ai -> score partials + LDS B-frags ----
  float rd0 = rcp_(den0), rd1 = rcp_(den1);
  f32x4 av0, av1;
  #pragma unroll
  for (int r=0;r<4;++r){ av0[r] = num0[r]*rd0; av1[r] = num1[r]*rd1; }
  {
    f32x4 vq4 = *(const f32x4*)&vqk[row0];
    f32x4 vk4 = *(const f32x4*)&vqk[64+row0];
    float pq0=0.f, pk0=0.f, pq1=0.f, pk1=0.f;
    #pragma unroll
    for (int r=0;r<4;++r){
      pq0 = fmaf(av0[r], vq4[r], pq0); pk0 = fmaf(av0[r], vk4[r], pk0);
      pq1 = fmaf(av1[r], vq4[r], pq1); pk1 = fmaf(av1[r], vk4[r], pk1);
    }
    pq0 += __shfl_xor(pq0,16,64); pq0 += __shfl_xor(pq0,32,64);
    pk0 += __shfl_xor(pk0,16,64); pk0 += __shfl_xor(pk0,32,64);
    pq1 += __shfl_xor(pq1,16,64); pq1 += __shfl_xor(pq1,32,64);
    pk1 += __shfl_xor(pk1,16,64); pk1 += __shfl_xor(pk1,32,64);
    if (lane < 16){
      attq[ht][sl] = pq0;    attk[ht][sl] = pk0;
      attq[ht][16+sl] = pq1; attk[ht][16+sl] = pk1;
    }
  }
  { f16x4 af0, af1;
    #pragma unroll
    for (int r=0;r<4;++r){ af0[r] = (_Float16)av0[r]; af1[r] = (_Float16)av1[r]; }
    const int cw = (((ht*2+(g>>1)) ^ s7))*8 + (g&1)*4;
    *(f16x4*)(h1s + sl*64      + cw) = af0;
    *(f16x4*)(h1s + (16+sl)*64 + cw) = af1; }
  __syncthreads();
  // ---- scores out (pre-scaled by LOG2E for exp2 in agg) ----
  if (tid < 32){
    float q4 = attq[0][tid]+attq[1][tid]+attq[2][tid]+attq[3][tid];
    float k4 = attk[0][tid]+attk[1][tid]+attk[2][tid]+attk[3][tid];
    sqT[tid*512 + n] = (q4 + vqk[128])*LOG2E;
    skT[tid*512 + n] = (k4 + vqk[129])*LOG2E;
  }
  // ---- proj = Ai @ W1^T + W1b via 2 MFMAs per seq-tile, store f16 ----
  {
    f16x8 a0 = wf8[5376 + (ht*2+0)*64 + lane];
    f16x8 a1 = wf8[5376 + (ht*2+1)*64 + lane];
    f16x8 b00 = *(const f16x8*)(h1s + sl*64      + ((g    ^s7))*8);
    f16x8 b01 = *(const f16x8*)(h1s + sl*64      + (((4+g)^s7))*8);
    f16x8 b10 = *(const f16x8*)(h1s + (16+sl)*64 + ((g    ^s7))*8);
    f16x8 b11 = *(const f16x8*)(h1s + (16+sl)*64 + (((4+g)^s7))*8);
    f32x4 P0 = *(const f32x4*)&W1b[row0];
    f32x4 P1 = P0;
    P0 = MFMA(a0,b00,P0); P0 = MFMA(a1,b01,P0);
    P1 = MFMA(a0,b10,P1); P1 = MFMA(a1,b11,P1);
    f16x4 pf0, pf1;
    #pragma unroll
    for (int r=0;r<4;++r){ pf0[r] = (_Float16)P0[r]; pf1[r] = (_Float16)P1[r]; }
    *(f16x4*)(projh + (size_t)(seq0+sl)*64    + row0) = pf0;
    *(f16x4*)(projh + (size_t)(seq0+16+sl)*64 + row0) = pf1;
  }
}

// ---------------- GAT aggregation: MFMA PV over (q x k) per batch-col ----------------
// grid 256 = 8 q-tiles(64) x 32 b; 256 thr, wave = q-sub of 16.
// O^T[d,q] = sum_k projT[d,k] * E[k-col q]; E computed in-register in B-frag layout.
__global__ __launch_bounds__(256) void gat_agg(
    const _Float16* __restrict__ projh,
    const float* __restrict__ sqT, const float* __restrict__ skT,
    float* __restrict__ out)
{
  __shared__ _Float16 pT[64*64];   // [d][k] chunk-XOR-swizzled, 8KB
  __shared__ float sks[512];
  const int tid  = threadIdx.x;
  const int lane = tid & 63;
  const int wv   = tid >> 6;
  const int b    = blockIdx.x & 31;
  const int qt   = blockIdx.x >> 5;
  const int sl   = lane & 15, g = lane >> 4;
  const int myq  = qt*64 + wv*16 + sl;
  const float sq_l = (myq < 500) ? sqT[b*512 + myq] : -1e30f;
  for (int j = tid; j < 512; j += 256) sks[j] = (j < 500) ? skT[b*512 + j] : -1e30f;

  f32x4 acc[4] = {{0,0,0,0},{0,0,0,0},{0,0,0,0},{0,0,0,0}};
  float den_l = 0.f;
  const int kr = tid & 63, dgrp = tid >> 6;

  // prefetch chunk 0
  f16x8 pv0 = f16x8_zero(), pv1 = f16x8_zero();
  if (kr < 500){
    const f16x8* pp = (const f16x8*)(projh + ((size_t)kr*32 + b)*64 + dgrp*16);
    pv0 = pp[0]; pv1 = pp[1];
  }

  #pragma unroll 1
  for (int kc=0; kc<8; ++kc){
    __syncthreads();   // pT free (previous chunk consumed)
    // transpose-write: element (k=kr, d=dgrp*16+j) -> byte d*128 + ((kr>>3 ^ d&7)<<4) + (kr&7)*2
    { char* base = (char*)pT;
      const int klo = (kr & 7) << 1, khi = kr >> 3;
      #pragma unroll
      for (int j=0;j<16;++j){
        int d = dgrp*16 + j;
        _Float16 v = (j<8) ? pv0[j] : pv1[j-8];
        *(_Float16*)(base + d*128 + (((khi ^ (d&7))) << 4) + klo) = v;
      } }
    __syncthreads();
    // prefetch next chunk (latency hides under compute)
    if (kc < 7){
      int node = (kc+1)*64 + kr;
      if (node < 500){
        const f16x8* pp = (const f16x8*)(projh + ((size_t)node*32 + b)*64 + dgrp*16);
        pv0 = pp[0]; pv1 = pp[1];
      } else { pv0 = f16x8_zero(); pv1 = f16x8_zero(); }
    }
    // compute: 2 k32-subchunks x 4 d-tiles
    #pragma unroll
    for (int kc32=0; kc32<2; ++kc32){
      const int kb = kc*64 + kc32*32 + g*8;
      float4 skv0 = *(const float4*)&sks[kb];
      float4 skv1 = *(const float4*)&sks[kb+4];
      float s[8] = {sq_l+skv0.x, sq_l+skv0.y, sq_l+skv0.z, sq_l+skv0.w,
                    sq_l+skv1.x, sq_l+skv1.y, sq_l+skv1.z, sq_l+skv1.w};
      f16x8 bf;
      #pragma unroll
      for (int e=0;e<8;++e){
        float sc = fmaxf(s[e], 0.01f*s[e]);   // leaky_relu (scale-commuting)
        float ev = exp2_(sc);
        den_l += ev;
        bf[e] = (_Float16)ev;
      }
      const char* base = (const char*)pT;
      #pragma unroll
      for (int dt=0; dt<4; ++dt){
        f16x8 a = *(const f16x8*)(base + (dt*16 + sl)*128 + (((kc32*4 + g) ^ (sl&7)) << 4));
        acc[dt] = MFMA(a, bf, acc[dt]);
      }
    }
  }
  den_l += __shfl_xor(den_l, 16, 64);
  den_l += __shfl_xor(den_l, 32, 64);
  const float rd = rcp_(den_l);
  if (myq < 500){
    #pragma unroll
    for (int dt=0; dt<4; ++dt){
      f32x4 o;
      #pragma unroll
      for (int r=0;r<4;++r) o[r] = fmaxf(acc[dt][r]*rd, 0.f);
      *(f32x4*)&out[((size_t)myq*32 + b)*64 + dt*16 + g*4] = o;
    }
  }
}

extern "C" void kernel_launch(void* const* d_in, const int* in_sizes, int n_in,
                              void* d_out, int out_size, void* d_ws, size_t ws_size,
                              hipStream_t stream) {
  const float* raw   = (const float*)d_in[0];
  const float* w1ih  = (const float*)d_in[1];
  const float* w1hh  = (const float*)d_in[2];
  const float* b1ih  = (const float*)d_in[3];
  const float* b1hh  = (const float*)d_in[4];
  const float* w2ih  = (const float*)d_in[5];
  const float* w2hh  = (const float*)d_in[6];
  const float* b2ih  = (const float*)d_in[7];
  const float* b2hh  = (const float*)d_in[8];
  const float* attW  = (const float*)d_in[9];
  const float* attb  = (const float*)d_in[10];
  const float* gWw   = (const float*)d_in[11];
  const float* gWb   = (const float*)d_in[12];
  const float* gu    = (const float*)d_in[13];
  const float* gW1   = (const float*)d_in[14];
  const float* gW1b  = (const float*)d_in[15];
  float* outp = (float*)d_out;

  char* wsb = (char*)d_ws;
  _Float16* projh = (_Float16*)wsb;                           // 2,048,000 B
  float*    sqT   = (float*)(wsb + 2048000);                  // 65,536 B [32][512]
  float*    skT   = (float*)(wsb + 2048000 + 65536);          // 65,536 B
  _Float16* wfh   = (_Float16*)(wsb + 2048000 + 131072);      // 94,208 B (5888 chunks)
  float*    vqk   = (float*)(wsb + 2048000 + 131072 + 94208); // 520 B

  wprep<<<185, 256, 0, stream>>>(w1ih, w1hh, w2ih, w2hh, b1ih, b1hh,
                                 gW1, gWw, gWb, gu, wfh, vqk);
  gru_mfma<<<500, 256, 0, stream>>>(raw, wfh, vqk, b1hh, b2ih, b2hh,
                                    attW, attb, gW1b, projh, sqT, skT);
  gat_agg<<<256, 256, 0, stream>>>(projh, sqT, skT, outp);
}